// Round 1
// baseline (390.272 us; speedup 1.0000x reference)
//
#include <hip/hip_runtime.h>

// PixCorr: per-row Pearson correlation of preds vs targets, mean over rows.
// preds/targets: fp32, N=256 rows, D=3*256*256=196608 elements per row.
// Memory-bound: 402.7 MB streamed once -> ~64us roofline at 6.3 TB/s.

constexpr int NROWS = 256;
constexpr int D     = 3 * 256 * 256;   // 196608
constexpr int D4    = D / 4;           // 49152 float4 per row
constexpr int TPB   = 1024;            // 16 waves per block, one block per row
constexpr double EPS = 1e-6;

__global__ __launch_bounds__(TPB) void row_corr_kernel(
        const float4* __restrict__ preds,
        const float4* __restrict__ targets,
        double* __restrict__ row_out)
{
    const int  row  = blockIdx.x;
    const int  tid  = threadIdx.x;
    const long base = (long)row * D4;

    // Per-thread moment accumulators in double (threshold is tight in abs
    // terms vs a ~1e-5 reference value; fp64 makes accumulation error moot).
    double sZ = 0.0, sB = 0.0, sZZ = 0.0, sBB = 0.0, sZB = 0.0;

    for (int i = tid; i < D4; i += TPB) {
        const float4 b4 = preds[base + i];    // B = preds
        const float4 z4 = targets[base + i];  // Z = targets
        double z, b;
        z = (double)z4.x; b = (double)b4.x;
        sZ += z; sB += b; sZZ = fma(z, z, sZZ); sBB = fma(b, b, sBB); sZB = fma(z, b, sZB);
        z = (double)z4.y; b = (double)b4.y;
        sZ += z; sB += b; sZZ = fma(z, z, sZZ); sBB = fma(b, b, sBB); sZB = fma(z, b, sZB);
        z = (double)z4.z; b = (double)b4.z;
        sZ += z; sB += b; sZZ = fma(z, z, sZZ); sBB = fma(b, b, sBB); sZB = fma(z, b, sZB);
        z = (double)z4.w; b = (double)b4.w;
        sZ += z; sB += b; sZZ = fma(z, z, sZZ); sBB = fma(b, b, sBB); sZB = fma(z, b, sZB);
    }

    // Wave (64-lane) shuffle reduction.
    #pragma unroll
    for (int off = 32; off > 0; off >>= 1) {
        sZ  += __shfl_down(sZ,  off);
        sB  += __shfl_down(sB,  off);
        sZZ += __shfl_down(sZZ, off);
        sBB += __shfl_down(sBB, off);
        sZB += __shfl_down(sZB, off);
    }

    constexpr int NWAVES = TPB / 64;
    __shared__ double sm[5][NWAVES];
    const int wave = tid >> 6;
    const int lane = tid & 63;
    if (lane == 0) {
        sm[0][wave] = sZ;  sm[1][wave] = sB;
        sm[2][wave] = sZZ; sm[3][wave] = sBB;
        sm[4][wave] = sZB;
    }
    __syncthreads();

    if (tid == 0) {
        double tZ = 0, tB = 0, tZZ = 0, tBB = 0, tZB = 0;
        #pragma unroll
        for (int w = 0; w < NWAVES; ++w) {
            tZ += sm[0][w]; tB += sm[1][w]; tZZ += sm[2][w];
            tBB += sm[3][w]; tZB += sm[4][w];
        }
        const double invD = 1.0 / (double)D;
        const double num  = tZB - tZ * tB * invD;
        const double varZ = fmax(tZZ - tZ * tZ * invD, 0.0);
        const double varB = fmax(tBB - tB * tB * invD, 0.0);
        const double den  = sqrt(varZ) * sqrt(varB) + EPS;  // matches ref: (|Z||B| + eps)
        row_out[row] = num / den;
    }
}

__global__ __launch_bounds__(NROWS) void mean_kernel(
        const double* __restrict__ row_out, float* __restrict__ out)
{
    const int tid = threadIdx.x;
    double v = row_out[tid];
    #pragma unroll
    for (int off = 32; off > 0; off >>= 1) v += __shfl_down(v, off);

    __shared__ double sm[NROWS / 64];
    const int wave = tid >> 6;
    const int lane = tid & 63;
    if (lane == 0) sm[wave] = v;
    __syncthreads();
    if (tid == 0) {
        double t = 0.0;
        #pragma unroll
        for (int w = 0; w < NROWS / 64; ++w) t += sm[w];
        out[0] = (float)(t / (double)NROWS);
    }
}

extern "C" void kernel_launch(void* const* d_in, const int* in_sizes, int n_in,
                              void* d_out, int out_size, void* d_ws, size_t ws_size,
                              hipStream_t stream) {
    const float4* preds   = (const float4*)d_in[0];
    const float4* targets = (const float4*)d_in[1];
    double* row_out = (double*)d_ws;   // 256 doubles = 2 KiB scratch
    float*  out     = (float*)d_out;

    hipLaunchKernelGGL(row_corr_kernel, dim3(NROWS), dim3(TPB), 0, stream,
                       preds, targets, row_out);
    hipLaunchKernelGGL(mean_kernel, dim3(1), dim3(NROWS), 0, stream,
                       row_out, out);
}